// Round 9
// baseline (8845.619 us; speedup 1.0000x reference)
//
#include <hip/hip_runtime.h>
#include <hip/hip_fp16.h>

// ONLSTM fused 2-layer recurrent kernel for MI355X (gfx950), round 12.
// Base: r11 (4637 us, the session's best: fresh PART slots + atomic-free
// epilogue on the r3 skeleton). Barrier/flag/publish semantics UNTOUCHED.
// Two changes:
//  1. Explicit 8-deep register prefetch of the sc1 h fragments in all GEMM
//     streams (r9's pipeline shape, but WITHOUT r9's toxic pre-GEMM polls,
//     which confounded that measurement). Raises in-flight coherent loads
//     from ~10 (compiler's conservative atomic scheduling at VGPR=92) to
//     ~16-32, attacking the ~2-3 us/step sc1 drain.
//  2. h0 ring 3 -> 4 slots: read slot (s+3)&3, write slot s&3. The layer0
//     anti-overwrite wait target lags one step (FA >= s-1) and becomes
//     almost-always pre-satisfied.

typedef _Float16 f16;
typedef _Float16 f16x8 __attribute__((ext_vector_type(8)));
typedef _Float16 f16x2 __attribute__((ext_vector_type(2)));
typedef float f32x4 __attribute__((ext_vector_type(4)));

#define NWG 256
#define AGENT __HIP_MEMORY_SCOPE_AGENT
#define MFMA16 __builtin_amdgcn_mfma_f32_16x16x32_f16

// coherent (sc1) 16B fragment load: two relaxed agent-scope u64 atomic loads
__device__ __forceinline__ f16x8 ld_frag(const f16* p) {
    union { unsigned long long u[2]; f16x8 v; } c;
    c.u[0] = __hip_atomic_load((const unsigned long long*)p, __ATOMIC_RELAXED, AGENT);
    c.u[1] = __hip_atomic_load(((const unsigned long long*)p) + 1, __ATOMIC_RELAXED, AGENT);
    return c.v;
}

// ---------------- pack kernels (unchanged, verified) ----------------
__global__ void onlstm_pack_w(const float* __restrict__ W, f16* __restrict__ dst,
                              int nkt, int krow0) {
    int idx = blockIdx.x * blockDim.x + threadIdx.x;
    int total = 128 * 3 * nkt * 64;
    if (idx >= total) return;
    int lane = idx & 63;
    int kt = (idx >> 6) % nkt;
    int ct = ((idx >> 6) / nkt) % 3;
    int w  = (idx >> 6) / (nkt * 3);
    int cc = lane & 15;
    int gate = 2 * ct + (cc >> 3);
    int col = gate * 1024 + (w << 3) + (cc & 7);
    int krow = krow0 + kt * 32 + ((lane >> 4) << 3);
    const float* src = W + (size_t)krow * 6144 + col;
    f16x8 v;
#pragma unroll
    for (int i = 0; i < 8; ++i) v[i] = (f16)src[(size_t)i * 6144];
    *(f16x8*)(dst + (size_t)idx * 8) = v;
}

__global__ void onlstm_pack_x(const float* __restrict__ x, f16* __restrict__ dst) {
    int idx = blockIdx.x * blockDim.x + threadIdx.x;
    if (idx >= 256 * 16 * 4 * 64) return;
    int lane = idx & 63;
    int rt = (idx >> 6) & 3;
    int kt = (idx >> 8) & 15;
    int t  = idx >> 12;
    int m = rt * 16 + (lane & 15);
    int k = kt * 32 + ((lane >> 4) << 3);
    const float* src = x + ((size_t)t * 64 + m) * 512 + k;
    f16x8 v;
#pragma unroll
    for (int i = 0; i < 8; ++i) v[i] = (f16)src[i];
    *(f16x8*)(dst + (size_t)idx * 8) = v;
}

__device__ __forceinline__ float fast_sigmoid(float x) {
    return 1.0f / (1.0f + __expf(-x));
}
__device__ __forceinline__ float fast_tanh(float x) {
    return 1.0f - 2.0f / (__expf(2.0f * x) + 1.0f);
}

// ---------------- main persistent kernel ----------------
// LDS: sB 147456 | sZ 64x49 f32 12544 | sPfx 2048 | sScl 1024 | sBias 256
__global__ __launch_bounds__(256, 1) void onlstm_main(
    const f16* __restrict__ WB0, const f16* __restrict__ WB1,
    const f16* __restrict__ WS1, const f16* __restrict__ XP,
    f16* __restrict__ H0P, f16* __restrict__ H1P,
    float* __restrict__ PARTS, int* __restrict__ FLAGS,
    const float* __restrict__ b0, const float* __restrict__ b1,
    float* __restrict__ out)
{
    extern __shared__ char smem[];
    f16*   sB    = (f16*)smem;
    float* sZ    = (float*)(smem + 147456);
    float* sPfx  = (float*)(smem + 160000);
    float* sScl  = (float*)(smem + 162048);
    float* sBias = (float*)(smem + 163072);

    const int tid = threadIdx.x;
    const int wg = blockIdx.x;
    const int layer = wg >> 7;
    const int w = wg & 127;
    const int lane = tid & 63;
    const int wv = tid >> 6;          // 0..3
    const int rtp = wv & 1;           // row-pair
    const int kh = wv >> 1;           // K-half
    const int j0 = w << 3;
    const int m_u = tid & 63;
    const int pr4 = tid >> 6;
    int* FA = FLAGS;                  // barrier-A flags, stride 16 ints (64B)
    int* FB = FLAGS + 4096;           // barrier-B flags

    // resident weights -> LDS (pre-kernel data: normal cached loads are safe)
    {
        const float4* s4 = (const float4*)(layer ? (WB1 + (size_t)w * (3 * 32 * 512))
                                                 : (WB0 + (size_t)w * (3 * 48 * 512)));
        float4* d4 = (float4*)sB;
        const int n = layer ? (3 * 32 * 64) : (3 * 48 * 64);
        for (int i = tid; i < n; i += 256) d4[i] = s4[i];
    }
    if (tid < 48) {
        int ct = tid >> 4, r = tid & 15;
        int gate = 2 * ct + (r >> 3);
        sBias[tid] = (layer ? b1 : b0)[gate * 1024 + j0 + (r & 7)];
    }
    float c0 = 0.f, c1 = 0.f;   // persistent cell state: (m_u, j0 + pr4*2 + {0,1})
    __syncthreads();

    for (int s = 0; s <= 256; ++s) {
        const int active = layer ? (s >= 1) : (s < 256);
        const int t = layer ? (s - 1) : s;
        const int hr = (s + 3) & 3;               // H0 read slot = h0(s-1), 4-ring
        float* PARTs = PARTS + (size_t)s * 32768; // fresh PART slot for step s

        f32x4 acc[2][3];
        if (active) {
            // ---------- GEMM (K-split across wave pairs) ----------
#pragma unroll
            for (int r = 0; r < 2; ++r)
#pragma unroll
                for (int c = 0; c < 3; ++c) { f32x4 z = {0.f,0.f,0.f,0.f}; acc[r][c] = z; }

            const f16* h0r = H0P + (size_t)hr * 65536;
            const int abase = rtp * 1024 + lane * 8;

            if (layer == 0) {
                if (kh == 0) {
                    const f16* A1 = XP + (size_t)t * 32768;
#pragma unroll 8
                    for (int kt = 0; kt < 16; ++kt) {
                        const f16* ap = A1 + (size_t)kt * 2048 + abase;
                        f16x8 a0 = *(const f16x8*)ap;          // XP: pre-kernel, cached
                        f16x8 a1 = *(const f16x8*)(ap + 512);
#pragma unroll
                        for (int ct = 0; ct < 3; ++ct) {
                            f16x8 b = *(const f16x8*)(sB + ((size_t)(ct * 48 + kt) * 64 + lane) * 8);
                            acc[0][ct] = MFMA16(a0, b, acc[0][ct], 0, 0, 0);
                            acc[1][ct] = MFMA16(a1, b, acc[1][ct], 0, 0, 0);
                        }
                    }
                    // h part: 8 kt fully prefetched (sc1)
                    f16x8 p0[8], p1[8];
#pragma unroll
                    for (int k = 0; k < 8; ++k) {
                        const f16* ap = h0r + (size_t)k * 2048 + abase;
                        p0[k] = ld_frag(ap);
                        p1[k] = ld_frag(ap + 512);
                    }
#pragma unroll
                    for (int k = 0; k < 8; ++k) {
#pragma unroll
                        for (int ct = 0; ct < 3; ++ct) {
                            f16x8 b = *(const f16x8*)(sB + ((size_t)(ct * 48 + 16 + k) * 64 + lane) * 8);
                            acc[0][ct] = MFMA16(p0[k], b, acc[0][ct], 0, 0, 0);
                            acc[1][ct] = MFMA16(p1[k], b, acc[1][ct], 0, 0, 0);
                        }
                    }
                } else {
                    // kt 8..31 in 3 chunks of 8 with rolling prefetch (sc1)
                    f16x8 p0[8], p1[8];
#pragma unroll
                    for (int k = 0; k < 8; ++k) {
                        const f16* ap = h0r + (size_t)(8 + k) * 2048 + abase;
                        p0[k] = ld_frag(ap);
                        p1[k] = ld_frag(ap + 512);
                    }
#pragma unroll
                    for (int c = 0; c < 3; ++c) {
#pragma unroll
                        for (int k = 0; k < 8; ++k) {
                            const int kt = 8 + c * 8 + k;
                            f16x8 a0 = p0[k], a1 = p1[k];
                            if (c < 2) {
                                const f16* ap = h0r + (size_t)(kt + 8) * 2048 + abase;
                                p0[k] = ld_frag(ap);
                                p1[k] = ld_frag(ap + 512);
                            }
#pragma unroll
                            for (int ct = 0; ct < 3; ++ct) {
                                f16x8 b = *(const f16x8*)(sB + ((size_t)(ct * 48 + 16 + kt) * 64 + lane) * 8);
                                acc[0][ct] = MFMA16(a0, b, acc[0][ct], 0, 0, 0);
                                acc[1][ct] = MFMA16(a1, b, acc[1][ct], 0, 0, 0);
                            }
                        }
                    }
                }
            } else {
                if (kh == 0) {
                    const f16* BS = WS1 + (size_t)w * (3 * 32 * 512);  // L2-hot, cached
                    f16x8 p0[8], p1[8];
#pragma unroll
                    for (int k = 0; k < 8; ++k) {
                        const f16* ap = h0r + (size_t)k * 2048 + abase;
                        p0[k] = ld_frag(ap);
                        p1[k] = ld_frag(ap + 512);
                    }
#pragma unroll
                    for (int c = 0; c < 4; ++c) {
#pragma unroll
                        for (int k = 0; k < 8; ++k) {
                            const int kt = c * 8 + k;
                            f16x8 a0 = p0[k], a1 = p1[k];
                            if (c < 3) {
                                const f16* ap = h0r + (size_t)(kt + 8) * 2048 + abase;
                                p0[k] = ld_frag(ap);
                                p1[k] = ld_frag(ap + 512);
                            }
#pragma unroll
                            for (int ct = 0; ct < 3; ++ct) {
                                f16x8 b = *(const f16x8*)(BS + ((size_t)(ct * 32 + kt) * 64 + lane) * 8);
                                acc[0][ct] = MFMA16(a0, b, acc[0][ct], 0, 0, 0);
                                acc[1][ct] = MFMA16(a1, b, acc[1][ct], 0, 0, 0);
                            }
                        }
                    }
                } else {
                    const f16* h1r = H1P + (size_t)(s & 1) * 65536;    // h1(s-2)
                    f16x8 p0[8], p1[8];
#pragma unroll
                    for (int k = 0; k < 8; ++k) {
                        const f16* ap = h1r + (size_t)k * 2048 + abase;
                        p0[k] = ld_frag(ap);
                        p1[k] = ld_frag(ap + 512);
                    }
#pragma unroll
                    for (int c = 0; c < 4; ++c) {
#pragma unroll
                        for (int k = 0; k < 8; ++k) {
                            const int kt = c * 8 + k;
                            f16x8 a0 = p0[k], a1 = p1[k];
                            if (c < 3) {
                                const f16* ap = h1r + (size_t)(kt + 8) * 2048 + abase;
                                p0[k] = ld_frag(ap);
                                p1[k] = ld_frag(ap + 512);
                            }
#pragma unroll
                            for (int ct = 0; ct < 3; ++ct) {
                                f16x8 b = *(const f16x8*)(sB + ((size_t)(ct * 32 + kt) * 64 + lane) * 8);
                                acc[0][ct] = MFMA16(a0, b, acc[0][ct], 0, 0, 0);
                                acc[1][ct] = MFMA16(a1, b, acc[1][ct], 0, 0, 0);
                            }
                        }
                    }
                }
            }
            // epilogue phase 1: kh=1 waves store partials (plain, disjoint rows)
            if (kh == 1) {
                const int mq = ((lane >> 4) << 2);
                const int colb = lane & 15;
#pragma unroll
                for (int r = 0; r < 2; ++r) {
                    int mrow = rtp * 32 + r * 16 + mq;
#pragma unroll
                    for (int ct = 0; ct < 3; ++ct) {
                        int col = ct * 16 + colb;
#pragma unroll
                        for (int q = 0; q < 4; ++q)
                            sZ[(mrow + q) * 49 + col] = acc[r][ct][q];
                    }
                }
            }
        }
        __syncthreads();   // kh1 partials visible
        if (active && kh == 0) {
            // epilogue phase 2: kh=0 waves RMW-add own acc + partial + bias
            const int mq = ((lane >> 4) << 2);
            const int colb = lane & 15;
#pragma unroll
            for (int r = 0; r < 2; ++r) {
                int mrow = rtp * 32 + r * 16 + mq;
#pragma unroll
                for (int ct = 0; ct < 3; ++ct) {
                    int col = ct * 16 + colb;
                    float bias = sBias[col];
#pragma unroll
                    for (int q = 0; q < 4; ++q) {
                        int idx = (mrow + q) * 49 + col;
                        sZ[idx] = sZ[idx] + acc[r][ct][q] + bias;
                    }
                }
            }
        }
        __syncthreads();

        if (active && tid < 128) {
            // local scan: exp + inclusive cumsum over 8 cols (g = f~ or i~)
            int g = tid >> 6, m = tid & 63;
            float run = 0.f;
            float* zp = sZ + m * 49 + 32 + g * 8;
#pragma unroll
            for (int jj = 0; jj < 8; ++jj) {
                float e = __expf(zp[jj]);
                run += e;
                zp[jj] = run;
            }
            __hip_atomic_store(&PARTs[((size_t)(layer * 2 + g) * 128 + w) * 64 + m], run,
                               __ATOMIC_RELAXED, AGENT);
        }

        // ---------- barrier A (layer-local, flag-based, fence-free) ----------
        __syncthreads();   // implicit vmcnt(0): all waves' sc1 stores at coherence point
        if (tid == 0)
            __hip_atomic_store(&FA[wg * 16], s + 1, __ATOMIC_RELAXED, AGENT);
        if (tid < 128) {
            const int* fp = &FA[(layer * 128 + tid) * 16];
            while (__hip_atomic_load(fp, __ATOMIC_RELAXED, AGENT) < s + 1) {}
        }
        __syncthreads();

        if (active) {
            // global prefix/total, half-split across the 4 waves.
            // PART slot is fresh this step: plain cached loads (L2-serviced).
            int g = pr4 & 1, half = pr4 >> 1;
            const float* pp = PARTs + ((size_t)(layer * 2 + g) * 128 + half * 64) * 64 + m_u;
            float pref = 0.f, tot = 0.f;
            int wrel = w - half * 64;
#pragma unroll 32
            for (int w2 = 0; w2 < 64; ++w2) {
                float v = pp[(size_t)w2 * 64];
                tot += v;
                pref += (w2 < wrel) ? v : 0.f;
            }
            float* q = sPfx + ((size_t)(m_u * 2 + g) * 2 + half) * 2;
            q[0] = pref; q[1] = tot;
        }
        __syncthreads();
        if (active && tid < 128) {
            int g = tid >> 6, m = tid & 63;
            float* q = sPfx + (size_t)(m * 2 + g) * 4;
            sScl[m * 4 + g * 2]     = q[0] + q[2];
            sScl[m * 4 + g * 2 + 1] = 1.0f / (q[1] + q[3]);
        }
        __syncthreads();

        if (active) {
            // ---------- gate math + state update (2 cols/thread) ----------
            float pf = sScl[m_u * 4 + 0], rf = sScl[m_u * 4 + 1];
            float pi = sScl[m_u * 4 + 2], ri = sScl[m_u * 4 + 3];
            int zb = m_u * 49;
            float cc[2] = {c0, c1}, hh[2];
#pragma unroll
            for (int q = 0; q < 2; ++q) {
                int jj = pr4 * 2 + q;
                float zi = sZ[zb + jj];
                float zf = sZ[zb + 8 + jj];
                float zg = sZ[zb + 16 + jj];
                float zo = sZ[zb + 24 + jj];
                float cft = sZ[zb + 32 + jj];
                float cit = sZ[zb + 40 + jj];
                float ftil = (pf + cft) * rf;
                float itil = 1.0f - (pi + cit) * ri;
                float om = ftil * itil;
                float fi = fast_sigmoid(zf);
                float ii = fast_sigmoid(zi);
                float oo = fast_sigmoid(zo);
                float ch = fast_tanh(zg);
                float fh = fi * om + (ftil - om);
                float ih = ii * om + (itil - om);
                float cn = fh * cc[q] + ih * ch;
                cc[q] = cn;
                hh[q] = oo * fast_tanh(cn);
            }
            c0 = cc[0]; c1 = cc[1];

            // publish h as A-fragments (fp16, sc1 write-through)
            int jfull = j0 + pr4 * 2;
            int ktp = jfull >> 5;
            int quad = (jfull >> 3) & 3;
            int i0 = jfull & 7;
            f16* HP = layer ? (H1P + (size_t)((s + 1) & 1) * 65536)
                            : (H0P + (size_t)(s & 3) * 65536);   // h0(s) -> slot s&3
            union { f16x2 h; int i; } hu;
            hu.h[0] = (f16)hh[0]; hu.h[1] = (f16)hh[1];
            __hip_atomic_store(
                (int*)(HP + ((size_t)(ktp * 4 + (m_u >> 4)) * 64 + (quad * 16 + (m_u & 15))) * 8 + i0),
                hu.i, __ATOMIC_RELAXED, AGENT);

            if (layer)
                *(float2*)(out + (size_t)t * 65536 + (size_t)m_u * 1024 + jfull) = make_float2(hh[0], hh[1]);
            if (t == 255) {
                *(float2*)(out + 16777216 + (size_t)layer * 65536 + (size_t)m_u * 1024 + jfull) = make_float2(hh[0], hh[1]);
                *(float2*)(out + 16908288 + (size_t)layer * 65536 + (size_t)m_u * 1024 + jfull) = make_float2(cc[0], cc[1]);
            }
        }

        // ---------- barrier B (split by layer, pipeline slack, fence-free) ----------
        if (s < 256) {
            __syncthreads();   // drains all waves' h sc1 stores
            if (tid == 0)
                __hip_atomic_store(&FB[wg * 16], s + 1, __ATOMIC_RELAXED, AGENT);
            if (layer == 0) {
                if (tid < 128) {
                    const int* fp = &FB[tid * 16];
                    while (__hip_atomic_load(fp, __ATOMIC_RELAXED, AGENT) < s + 1) {}
                } else {
                    // anti-overwrite (4-ring): before any layer0 WG enters step
                    // s+1 (write h0(s+1) over h0(s-3)), layer1 must have
                    // finished GEMM of step s-2 -> FA[layer1] >= s-1.
                    const int* fp = &FA[tid * 16];
                    while (__hip_atomic_load(fp, __ATOMIC_RELAXED, AGENT) < s - 1) {}
                }
            } else {
                const int* fp = &FB[tid * 16];
                while (__hip_atomic_load(fp, __ATOMIC_RELAXED, AGENT) < s + 1) {}
            }
            __syncthreads();
        }
    }
}

// ---------------- launch ----------------
extern "C" void kernel_launch(void* const* d_in, const int* in_sizes, int n_in,
                              void* d_out, int out_size, void* d_ws, size_t ws_size,
                              hipStream_t stream) {
    const float* x  = (const float*)d_in[0];
    const float* W0 = (const float*)d_in[1];
    const float* b0 = (const float*)d_in[2];
    const float* W1 = (const float*)d_in[3];
    const float* b1 = (const float*)d_in[4];
    float* out = (float*)d_out;

    char* ws = (char*)d_ws;
    f16* WB0     = (f16*)(ws + 0);           // 18874368
    f16* WB1     = (f16*)(ws + 18874368);    // 12582912
    f16* WS1     = (f16*)(ws + 31457280);    // 12582912
    f16* XP      = (f16*)(ws + 44040192);    // 16777216
    f16* H0P     = (f16*)(ws + 60817408);    // 4 x 131072 = 524288 (4-ring)
    f16* H1P     = (f16*)(ws + 61341696);    // 2 x 131072 = 262144
    int* FLAGS   = (int*)(ws + 61603840);    // 32768
    float* PARTS = (float*)(ws + 61636608);  // 257 x 131072 = 33685504
                                             // end ~95.3 MB < 128.35 MB proven

    hipMemsetAsync(H0P, 0, 524288, stream);
    hipMemsetAsync(H1P, 0, 262144, stream);
    hipMemsetAsync(FLAGS, 0, 32768, stream);

    {   int n = 128 * 3 * 48 * 64;
        onlstm_pack_w<<<(n + 255) / 256, 256, 0, stream>>>(W0, WB0, 48, 0); }
    {   int n = 128 * 3 * 32 * 64;
        onlstm_pack_w<<<(n + 255) / 256, 256, 0, stream>>>(W1, WB1, 32, 1024); }
    {   int n = 128 * 3 * 32 * 64;
        onlstm_pack_w<<<(n + 255) / 256, 256, 0, stream>>>(W1, WS1, 32, 0); }
    {   int n = 256 * 16 * 4 * 64;
        onlstm_pack_x<<<(n + 255) / 256, 256, 0, stream>>>(x, XP); }

    const int smem_bytes = 163328;
    hipFuncSetAttribute((const void*)onlstm_main,
                        hipFuncAttributeMaxDynamicSharedMemorySize, smem_bytes);
    onlstm_main<<<NWG, 256, smem_bytes, stream>>>(WB0, WB1, WS1, XP, H0P, H1P,
                                                  PARTS, FLAGS, b0, b1, out);
}

// Round 10
// 6339.186 us; speedup vs baseline: 1.3954x; 1.3954x over previous
//
#include <hip/hip_runtime.h>
#include <hip/hip_fp16.h>

// ONLSTM fused 2-layer recurrent kernel for MI355X (gfx950), round 13.
// r12 post-mortem: explicit sc1 prefetch batches are toxic (2nd confirmation;
// 8658 vs 4637). Compiler's interleaved load/MFMA schedule is optimal for
// coherent streams -- GEMM bodies stay in r11's form, forever.
// r13: ONE variable on the r11 base -- h read path. r8 tested cached
// fresh-slot h reads on the r3 base (neutral), but r3 carried ~5us/step of
// serial junk (sc1 PART gather, LDS-atomic epilogue) that r11 removed; the
// h-latency term may have been hidden. Retest on r11:
//   FRESH=1 (ws >= 161906688 B): h fresh slot per step; writers keep sc1
//     (drained before FB publish), readers are PLAIN CACHED loads (cold
//     addresses -> first miss fills L2 with fresh data; r8-proven).
//   FRESH=0: exact r11 (4637 us) fallback.
// Barriers/flags/epilogue/PART identical to r11 in both variants.

typedef _Float16 f16;
typedef _Float16 f16x8 __attribute__((ext_vector_type(8)));
typedef _Float16 f16x2 __attribute__((ext_vector_type(2)));
typedef float f32x4 __attribute__((ext_vector_type(4)));

#define NWG 256
#define AGENT __HIP_MEMORY_SCOPE_AGENT
#define MFMA16 __builtin_amdgcn_mfma_f32_16x16x32_f16

// coherent (sc1) 16B fragment load: two relaxed agent-scope u64 atomic loads
__device__ __forceinline__ f16x8 ld_frag(const f16* p) {
    union { unsigned long long u[2]; f16x8 v; } c;
    c.u[0] = __hip_atomic_load((const unsigned long long*)p, __ATOMIC_RELAXED, AGENT);
    c.u[1] = __hip_atomic_load(((const unsigned long long*)p) + 1, __ATOMIC_RELAXED, AGENT);
    return c.v;
}

template<int FRESH>
__device__ __forceinline__ f16x8 ld_h(const f16* p) {
    if constexpr (FRESH) return *(const f16x8*)p;   // cold address: L2 fill is fresh
    else return ld_frag(p);                          // ring reuse: must bypass L2
}

// ---------------- pack kernels (unchanged, verified) ----------------
__global__ void onlstm_pack_w(const float* __restrict__ W, f16* __restrict__ dst,
                              int nkt, int krow0) {
    int idx = blockIdx.x * blockDim.x + threadIdx.x;
    int total = 128 * 3 * nkt * 64;
    if (idx >= total) return;
    int lane = idx & 63;
    int kt = (idx >> 6) % nkt;
    int ct = ((idx >> 6) / nkt) % 3;
    int w  = (idx >> 6) / (nkt * 3);
    int cc = lane & 15;
    int gate = 2 * ct + (cc >> 3);
    int col = gate * 1024 + (w << 3) + (cc & 7);
    int krow = krow0 + kt * 32 + ((lane >> 4) << 3);
    const float* src = W + (size_t)krow * 6144 + col;
    f16x8 v;
#pragma unroll
    for (int i = 0; i < 8; ++i) v[i] = (f16)src[(size_t)i * 6144];
    *(f16x8*)(dst + (size_t)idx * 8) = v;
}

__global__ void onlstm_pack_x(const float* __restrict__ x, f16* __restrict__ dst) {
    int idx = blockIdx.x * blockDim.x + threadIdx.x;
    if (idx >= 256 * 16 * 4 * 64) return;
    int lane = idx & 63;
    int rt = (idx >> 6) & 3;
    int kt = (idx >> 8) & 15;
    int t  = idx >> 12;
    int m = rt * 16 + (lane & 15);
    int k = kt * 32 + ((lane >> 4) << 3);
    const float* src = x + ((size_t)t * 64 + m) * 512 + k;
    f16x8 v;
#pragma unroll
    for (int i = 0; i < 8; ++i) v[i] = (f16)src[i];
    *(f16x8*)(dst + (size_t)idx * 8) = v;
}

__device__ __forceinline__ float fast_sigmoid(float x) {
    return 1.0f / (1.0f + __expf(-x));
}
__device__ __forceinline__ float fast_tanh(float x) {
    return 1.0f - 2.0f / (__expf(2.0f * x) + 1.0f);
}

// ---------------- main persistent kernel ----------------
// LDS: sB 147456 | sZ 64x49 f32 12544 | sPfx 2048 | sScl 1024 | sBias 256
template<int FRESH>
__global__ __launch_bounds__(256, 1) void onlstm_main(
    const f16* __restrict__ WB0, const f16* __restrict__ WB1,
    const f16* __restrict__ WS1, const f16* __restrict__ XP,
    f16* __restrict__ H0P, f16* __restrict__ H1P,
    float* __restrict__ PARTS, int* __restrict__ FLAGS,
    const float* __restrict__ b0, const float* __restrict__ b1,
    float* __restrict__ out)
{
    extern __shared__ char smem[];
    f16*   sB    = (f16*)smem;
    float* sZ    = (float*)(smem + 147456);
    float* sPfx  = (float*)(smem + 160000);
    float* sScl  = (float*)(smem + 162048);
    float* sBias = (float*)(smem + 163072);

    const int tid = threadIdx.x;
    const int wg = blockIdx.x;
    const int layer = wg >> 7;
    const int w = wg & 127;
    const int lane = tid & 63;
    const int wv = tid >> 6;          // 0..3
    const int rtp = wv & 1;           // row-pair
    const int kh = wv >> 1;           // K-half
    const int j0 = w << 3;
    const int m_u = tid & 63;
    const int pr4 = tid >> 6;
    int* FA = FLAGS;                  // barrier-A flags, stride 16 ints (64B)
    int* FB = FLAGS + 4096;           // barrier-B flags

    // resident weights -> LDS (pre-kernel data: normal cached loads are safe)
    {
        const float4* s4 = (const float4*)(layer ? (WB1 + (size_t)w * (3 * 32 * 512))
                                                 : (WB0 + (size_t)w * (3 * 48 * 512)));
        float4* d4 = (float4*)sB;
        const int n = layer ? (3 * 32 * 64) : (3 * 48 * 64);
        for (int i = tid; i < n; i += 256) d4[i] = s4[i];
    }
    if (tid < 48) {
        int ct = tid >> 4, r = tid & 15;
        int gate = 2 * ct + (r >> 3);
        sBias[tid] = (layer ? b1 : b0)[gate * 1024 + j0 + (r & 7)];
    }
    float c0 = 0.f, c1 = 0.f;   // persistent cell state: (m_u, j0 + pr4*2 + {0,1})
    __syncthreads();

    for (int s = 0; s <= 256; ++s) {
        const int active = layer ? (s >= 1) : (s < 256);
        const int t = layer ? (s - 1) : s;
        const int hr = FRESH ? s : ((s + 2) % 3);  // H0 read slot = h0(s-1)
        float* PARTs = PARTS + (size_t)s * 32768;  // fresh PART slot for step s

        f32x4 acc[2][3];
        if (active) {
            // ---------- GEMM (K-split across wave pairs) ----------
#pragma unroll
            for (int r = 0; r < 2; ++r)
#pragma unroll
                for (int c = 0; c < 3; ++c) { f32x4 z = {0.f,0.f,0.f,0.f}; acc[r][c] = z; }

            const f16* h0r = H0P + (size_t)hr * 65536;
            const int abase = rtp * 1024 + lane * 8;

            if (layer == 0) {
                if (kh == 0) {
                    const f16* A1 = XP + (size_t)t * 32768;
#pragma unroll 8
                    for (int kt = 0; kt < 16; ++kt) {
                        const f16* ap = A1 + (size_t)kt * 2048 + abase;
                        f16x8 a0 = *(const f16x8*)ap;          // XP: pre-kernel, cached
                        f16x8 a1 = *(const f16x8*)(ap + 512);
#pragma unroll
                        for (int ct = 0; ct < 3; ++ct) {
                            f16x8 b = *(const f16x8*)(sB + ((size_t)(ct * 48 + kt) * 64 + lane) * 8);
                            acc[0][ct] = MFMA16(a0, b, acc[0][ct], 0, 0, 0);
                            acc[1][ct] = MFMA16(a1, b, acc[1][ct], 0, 0, 0);
                        }
                    }
#pragma unroll 8
                    for (int kt = 0; kt < 8; ++kt) {
                        const f16* ap = h0r + (size_t)kt * 2048 + abase;
                        f16x8 a0 = ld_h<FRESH>(ap);
                        f16x8 a1 = ld_h<FRESH>(ap + 512);
#pragma unroll
                        for (int ct = 0; ct < 3; ++ct) {
                            f16x8 b = *(const f16x8*)(sB + ((size_t)(ct * 48 + 16 + kt) * 64 + lane) * 8);
                            acc[0][ct] = MFMA16(a0, b, acc[0][ct], 0, 0, 0);
                            acc[1][ct] = MFMA16(a1, b, acc[1][ct], 0, 0, 0);
                        }
                    }
                } else {
#pragma unroll 8
                    for (int kt = 8; kt < 32; ++kt) {
                        const f16* ap = h0r + (size_t)kt * 2048 + abase;
                        f16x8 a0 = ld_h<FRESH>(ap);
                        f16x8 a1 = ld_h<FRESH>(ap + 512);
#pragma unroll
                        for (int ct = 0; ct < 3; ++ct) {
                            f16x8 b = *(const f16x8*)(sB + ((size_t)(ct * 48 + 16 + kt) * 64 + lane) * 8);
                            acc[0][ct] = MFMA16(a0, b, acc[0][ct], 0, 0, 0);
                            acc[1][ct] = MFMA16(a1, b, acc[1][ct], 0, 0, 0);
                        }
                    }
                }
            } else {
                if (kh == 0) {
                    const f16* BS = WS1 + (size_t)w * (3 * 32 * 512);  // pre-kernel, cached
#pragma unroll 8
                    for (int kt = 0; kt < 32; ++kt) {
                        const f16* ap = h0r + (size_t)kt * 2048 + abase;
                        f16x8 a0 = ld_h<FRESH>(ap);
                        f16x8 a1 = ld_h<FRESH>(ap + 512);
#pragma unroll
                        for (int ct = 0; ct < 3; ++ct) {
                            f16x8 b = *(const f16x8*)(BS + ((size_t)(ct * 32 + kt) * 64 + lane) * 8);
                            acc[0][ct] = MFMA16(a0, b, acc[0][ct], 0, 0, 0);
                            acc[1][ct] = MFMA16(a1, b, acc[1][ct], 0, 0, 0);
                        }
                    }
                } else {
                    // h1(s-2): FRESH -> slot s-1; ring -> slot s&1
                    const f16* h1r = H1P + (size_t)(FRESH ? (s - 1) : (s & 1)) * 65536;
#pragma unroll 8
                    for (int kt = 0; kt < 32; ++kt) {
                        const f16* ap = h1r + (size_t)kt * 2048 + abase;
                        f16x8 a0 = ld_h<FRESH>(ap);
                        f16x8 a1 = ld_h<FRESH>(ap + 512);
#pragma unroll
                        for (int ct = 0; ct < 3; ++ct) {
                            f16x8 b = *(const f16x8*)(sB + ((size_t)(ct * 32 + kt) * 64 + lane) * 8);
                            acc[0][ct] = MFMA16(a0, b, acc[0][ct], 0, 0, 0);
                            acc[1][ct] = MFMA16(a1, b, acc[1][ct], 0, 0, 0);
                        }
                    }
                }
            }
            // epilogue phase 1: kh=1 waves store partials (plain, disjoint rows)
            if (kh == 1) {
                const int mq = ((lane >> 4) << 2);
                const int colb = lane & 15;
#pragma unroll
                for (int r = 0; r < 2; ++r) {
                    int mrow = rtp * 32 + r * 16 + mq;
#pragma unroll
                    for (int ct = 0; ct < 3; ++ct) {
                        int col = ct * 16 + colb;
#pragma unroll
                        for (int q = 0; q < 4; ++q)
                            sZ[(mrow + q) * 49 + col] = acc[r][ct][q];
                    }
                }
            }
        }
        __syncthreads();   // kh1 partials visible
        if (active && kh == 0) {
            // epilogue phase 2: kh=0 waves RMW-add own acc + partial + bias
            const int mq = ((lane >> 4) << 2);
            const int colb = lane & 15;
#pragma unroll
            for (int r = 0; r < 2; ++r) {
                int mrow = rtp * 32 + r * 16 + mq;
#pragma unroll
                for (int ct = 0; ct < 3; ++ct) {
                    int col = ct * 16 + colb;
                    float bias = sBias[col];
#pragma unroll
                    for (int q = 0; q < 4; ++q) {
                        int idx = (mrow + q) * 49 + col;
                        sZ[idx] = sZ[idx] + acc[r][ct][q] + bias;
                    }
                }
            }
        }
        __syncthreads();

        if (active && tid < 128) {
            // local scan: exp + inclusive cumsum over 8 cols (g = f~ or i~)
            int g = tid >> 6, m = tid & 63;
            float run = 0.f;
            float* zp = sZ + m * 49 + 32 + g * 8;
#pragma unroll
            for (int jj = 0; jj < 8; ++jj) {
                float e = __expf(zp[jj]);
                run += e;
                zp[jj] = run;
            }
            __hip_atomic_store(&PARTs[((size_t)(layer * 2 + g) * 128 + w) * 64 + m], run,
                               __ATOMIC_RELAXED, AGENT);
        }

        // ---------- barrier A (layer-local, flag-based, fence-free) ----------
        __syncthreads();   // implicit vmcnt(0): all waves' sc1 stores at coherence point
        if (tid == 0)
            __hip_atomic_store(&FA[wg * 16], s + 1, __ATOMIC_RELAXED, AGENT);
        if (tid < 128) {
            const int* fp = &FA[(layer * 128 + tid) * 16];
            while (__hip_atomic_load(fp, __ATOMIC_RELAXED, AGENT) < s + 1) {}
        }
        __syncthreads();

        if (active) {
            // global prefix/total, half-split across the 4 waves.
            // PART slot is fresh this step: plain cached loads (L2-serviced).
            int g = pr4 & 1, half = pr4 >> 1;
            const float* pp = PARTs + ((size_t)(layer * 2 + g) * 128 + half * 64) * 64 + m_u;
            float pref = 0.f, tot = 0.f;
            int wrel = w - half * 64;
#pragma unroll 32
            for (int w2 = 0; w2 < 64; ++w2) {
                float v = pp[(size_t)w2 * 64];
                tot += v;
                pref += (w2 < wrel) ? v : 0.f;
            }
            float* q = sPfx + ((size_t)(m_u * 2 + g) * 2 + half) * 2;
            q[0] = pref; q[1] = tot;
        }
        __syncthreads();
        if (active && tid < 128) {
            int g = tid >> 6, m = tid & 63;
            float* q = sPfx + (size_t)(m * 2 + g) * 4;
            sScl[m * 4 + g * 2]     = q[0] + q[2];
            sScl[m * 4 + g * 2 + 1] = 1.0f / (q[1] + q[3]);
        }
        __syncthreads();

        if (active) {
            // ---------- gate math + state update (2 cols/thread) ----------
            float pf = sScl[m_u * 4 + 0], rf = sScl[m_u * 4 + 1];
            float pi = sScl[m_u * 4 + 2], ri = sScl[m_u * 4 + 3];
            int zb = m_u * 49;
            float cc[2] = {c0, c1}, hh[2];
#pragma unroll
            for (int q = 0; q < 2; ++q) {
                int jj = pr4 * 2 + q;
                float zi = sZ[zb + jj];
                float zf = sZ[zb + 8 + jj];
                float zg = sZ[zb + 16 + jj];
                float zo = sZ[zb + 24 + jj];
                float cft = sZ[zb + 32 + jj];
                float cit = sZ[zb + 40 + jj];
                float ftil = (pf + cft) * rf;
                float itil = 1.0f - (pi + cit) * ri;
                float om = ftil * itil;
                float fi = fast_sigmoid(zf);
                float ii = fast_sigmoid(zi);
                float oo = fast_sigmoid(zo);
                float ch = fast_tanh(zg);
                float fh = fi * om + (ftil - om);
                float ih = ii * om + (itil - om);
                float cn = fh * cc[q] + ih * ch;
                cc[q] = cn;
                hh[q] = oo * fast_tanh(cn);
            }
            c0 = cc[0]; c1 = cc[1];

            // publish h as A-fragments (fp16, sc1 write-through)
            int jfull = j0 + pr4 * 2;
            int ktp = jfull >> 5;
            int quad = (jfull >> 3) & 3;
            int i0 = jfull & 7;
            // layer0 writes h0(s):   FRESH -> slot s+1; ring -> slot s%3
            // layer1 writes h1(s-1): FRESH -> slot s;   ring -> slot (s+1)&1
            f16* HP = layer ? (H1P + (size_t)(FRESH ? s : ((s + 1) & 1)) * 65536)
                            : (H0P + (size_t)(FRESH ? (s + 1) : (s % 3)) * 65536);
            union { f16x2 h; int i; } hu;
            hu.h[0] = (f16)hh[0]; hu.h[1] = (f16)hh[1];
            __hip_atomic_store(
                (int*)(HP + ((size_t)(ktp * 4 + (m_u >> 4)) * 64 + (quad * 16 + (m_u & 15))) * 8 + i0),
                hu.i, __ATOMIC_RELAXED, AGENT);

            if (layer)
                *(float2*)(out + (size_t)t * 65536 + (size_t)m_u * 1024 + jfull) = make_float2(hh[0], hh[1]);
            if (t == 255) {
                *(float2*)(out + 16777216 + (size_t)layer * 65536 + (size_t)m_u * 1024 + jfull) = make_float2(hh[0], hh[1]);
                *(float2*)(out + 16908288 + (size_t)layer * 65536 + (size_t)m_u * 1024 + jfull) = make_float2(cc[0], cc[1]);
            }
        }

        // ---------- barrier B (split by layer, pipeline slack, fence-free) ----------
        if (s < 256) {
            __syncthreads();   // drains all waves' h sc1 stores
            if (tid == 0)
                __hip_atomic_store(&FB[wg * 16], s + 1, __ATOMIC_RELAXED, AGENT);
            if (layer == 0) {
                if (tid < 128) {
                    const int* fp = &FB[tid * 16];
                    while (__hip_atomic_load(fp, __ATOMIC_RELAXED, AGENT) < s + 1) {}
                } else if constexpr (!FRESH) {
                    // ring anti-overwrite: layer1 must have finished GEMM of step s-1
                    const int* fp = &FA[tid * 16];
                    while (__hip_atomic_load(fp, __ATOMIC_RELAXED, AGENT) < s) {}
                }
            } else {
                const int* fp = &FB[tid * 16];
                while (__hip_atomic_load(fp, __ATOMIC_RELAXED, AGENT) < s + 1) {}
            }
            __syncthreads();
        }
    }
}

// ---------------- launch ----------------
extern "C" void kernel_launch(void* const* d_in, const int* in_sizes, int n_in,
                              void* d_out, int out_size, void* d_ws, size_t ws_size,
                              hipStream_t stream) {
    const float* x  = (const float*)d_in[0];
    const float* W0 = (const float*)d_in[1];
    const float* b0 = (const float*)d_in[2];
    const float* W1 = (const float*)d_in[3];
    const float* b1 = (const float*)d_in[4];
    float* out = (float*)d_out;

    char* ws = (char*)d_ws;
    f16* WB0 = (f16*)(ws + 0);           // 18874368
    f16* WB1 = (f16*)(ws + 18874368);    // 12582912
    f16* WS1 = (f16*)(ws + 31457280);    // 12582912
    f16* XP  = (f16*)(ws + 44040192);    // 16777216

    // FRESH needs 161906688 B; fallback = exact r11 layout (95.3 MB).
    const int fresh = (ws_size >= (size_t)161906688) ? 1 : 0;

    f16* H0P; f16* H1P; float* PARTS; int* FLAGS;
    if (fresh) {
        H0P   = (f16*)(ws + 60817408);      // 257 x 131072 = 33685504
        H1P   = (f16*)(ws + 94502912);      // 257 x 131072 = 33685504
        PARTS = (float*)(ws + 128188416);   // 257 x 131072 = 33685504
        FLAGS = (int*)(ws + 161873920);     // 32768
        hipMemsetAsync(H0P, 0, 131072, stream);   // slot 0 = h0(-1) = 0
        hipMemsetAsync(H1P, 0, 131072, stream);   // slot 0 = h1(-1) = 0
    } else {
        H0P   = (f16*)(ws + 60817408);      // 3 x 131072
        H1P   = (f16*)(ws + 61210624);      // 2 x 131072
        FLAGS = (int*)(ws + 61603840);      // 32768
        PARTS = (float*)(ws + 61636608);    // 257 x 131072
        hipMemsetAsync(H0P, 0, 393216, stream);
        hipMemsetAsync(H1P, 0, 262144, stream);
    }
    hipMemsetAsync(FLAGS, 0, 32768, stream);

    {   int n = 128 * 3 * 48 * 64;
        onlstm_pack_w<<<(n + 255) / 256, 256, 0, stream>>>(W0, WB0, 48, 0); }
    {   int n = 128 * 3 * 32 * 64;
        onlstm_pack_w<<<(n + 255) / 256, 256, 0, stream>>>(W1, WB1, 32, 1024); }
    {   int n = 128 * 3 * 32 * 64;
        onlstm_pack_w<<<(n + 255) / 256, 256, 0, stream>>>(W1, WS1, 32, 0); }
    {   int n = 256 * 16 * 4 * 64;
        onlstm_pack_x<<<(n + 255) / 256, 256, 0, stream>>>(x, XP); }

    const int smem_bytes = 163328;
    if (fresh) {
        hipFuncSetAttribute((const void*)onlstm_main<1>,
                            hipFuncAttributeMaxDynamicSharedMemorySize, smem_bytes);
        onlstm_main<1><<<NWG, 256, smem_bytes, stream>>>(WB0, WB1, WS1, XP, H0P, H1P,
                                                         PARTS, FLAGS, b0, b1, out);
    } else {
        hipFuncSetAttribute((const void*)onlstm_main<0>,
                            hipFuncAttributeMaxDynamicSharedMemorySize, smem_bytes);
        onlstm_main<0><<<NWG, 256, smem_bytes, stream>>>(WB0, WB1, WS1, XP, H0P, H1P,
                                                         PARTS, FLAGS, b0, b1, out);
    }
}